// Round 7
// baseline (138.435 us; speedup 1.0000x reference)
//
#include <hip/hip_runtime.h>
#include <math.h>

// Problem constants
#define BH 2
#define HH 96
#define WW 96
#define NPIX (BH*HH*WW)

// Tile geometry
#define TH 8            // tile rows (pixels)
#define TW 4            // tile cols (pixels)  -> 32 px/block
#define NH 140          // real halo pixels: (8+6)*(4+6)
#define NHP 160         // padded halo rows

#define NEGBIG (-3.0e38f)

typedef __attribute__((ext_vector_type(8))) short short8;
typedef __attribute__((ext_vector_type(4))) float f32x4;

__device__ __forceinline__ unsigned short f2bf(float f) {
    union { float f; unsigned u; } a; a.f = f;
    return (unsigned short)((a.u + 0x7FFFu + ((a.u >> 16) & 1u)) >> 16);
}
__device__ __forceinline__ unsigned packbf(float x, float y) {
    return (unsigned)f2bf(x) | ((unsigned)f2bf(y) << 16);
}

// ---------------------------------------------------------------------------
// Dispatch A (tiny): weights fp32 -> transposed bf16.
//   WqT/WkT [64][128], WvT [128][128] at wbase. 128 blocks.
// ---------------------------------------------------------------------------
__global__ __launch_bounds__(256) void wprep_kernel(
    const float* __restrict__ Wq, const float* __restrict__ Wk,
    const float* __restrict__ Wv, unsigned short* __restrict__ wbase)
{
    const int e = blockIdx.x * 256 + threadIdx.x;      // 0..32767
    if (e < 8192)       { wbase[e] = f2bf(Wq[(e & 127) * 64 + (e >> 7)]); }
    else if (e < 16384) { const int t = e - 8192;
                          wbase[e] = f2bf(Wk[(t & 127) * 64 + (t >> 7)]); }
    else                { const int t = e - 16384;
                          wbase[e] = f2bf(Wv[(t & 127) * 128 + (t >> 7)]); }
}

// ---------------------------------------------------------------------------
// Dispatch B: fused q+k projection -> q_bf/k_bf [NPIX][64] bf16.
// 576 blocks x 4 independent waves (no LDS/barriers). B-frags are b128
// loads from the pre-transposed L1-hot WqT/WkT.
// ---------------------------------------------------------------------------
__global__ __launch_bounds__(256) void proj_kernel(
    const float* __restrict__ Qg, const float* __restrict__ Kg,
    const unsigned short* __restrict__ wbase,
    const float* __restrict__ bq, const float* __restrict__ bk,
    unsigned short* __restrict__ q_bf, unsigned short* __restrict__ k_bf)
{
    const int tid  = threadIdx.x;
    const int lane = tid & 63;
    const int wvv  = tid >> 6;
    const int gw   = blockIdx.x * 4 + wvv;         // 0..2303
    const bool isq = gw < 1152;
    const int row0 = (isq ? gw : gw - 1152) * 16;

    const float* __restrict__ X = isq ? Qg : Kg;
    const unsigned short* __restrict__ WT = isq ? wbase : (wbase + 8192);
    const float* __restrict__ bia = isq ? bq : bk;
    unsigned short* __restrict__ Y = isq ? q_bf : k_bf;

    const int qd = lane >> 4, m = lane & 15;

    short8 afr[4];
    #pragma unroll
    for (int ks = 0; ks < 4; ++ks) {
        const float4* __restrict__ src = reinterpret_cast<const float4*>(
            X + (size_t)(row0 + m) * 128 + ks * 32 + qd * 8);
        const float4 a0 = src[0], a1 = src[1];
        short8 f;
        f[0] = (short)f2bf(a0.x); f[1] = (short)f2bf(a0.y);
        f[2] = (short)f2bf(a0.z); f[3] = (short)f2bf(a0.w);
        f[4] = (short)f2bf(a1.x); f[5] = (short)f2bf(a1.y);
        f[6] = (short)f2bf(a1.z); f[7] = (short)f2bf(a1.w);
        afr[ks] = f;
    }

    #pragma unroll
    for (int n = 0; n < 4; ++n) {
        f32x4 acc = {};
        #pragma unroll
        for (int ks = 0; ks < 4; ++ks) {
            const short8 bfr = *reinterpret_cast<const short8*>(
                WT + (n * 16 + m) * 128 + ks * 32 + qd * 8);
            acc = __builtin_amdgcn_mfma_f32_16x16x32_bf16(afr[ks], bfr, acc, 0, 0, 0);
        }
        const int col = n * 16 + m;
        const float bb = bia[col];
        #pragma unroll
        for (int r = 0; r < 4; ++r)
            Y[(size_t)(row0 + qd * 4 + r) * 64 + col] = f2bf(acc[r] + bb);
    }
}

// ---------------------------------------------------------------------------
// Dispatch C: neighborhood attention + out-projection.
// 576 blocks x 256 thr (4 waves: mt = wv&1 row-half, ng = wv>>1 col-half).
// V halo staged in LDS [halo][128] bf16 with qd-rotation swizzle ->
// PV B-frags are conflict-free ds_read_u16. Each wave computes ALL 10
// score n-tiles (redundant MFMA is free) -> in-wave softmax, no partial
// exchange. Only 2 barriers.
// LDS (u16 idx): VS [160][128] @0 (20480) | PS [32][168] @20480 (5376)
//                AS [32][136] @25856 (4352) -> 30208 u16 = 60416 B.
// ---------------------------------------------------------------------------
#define VS_OFF 0
#define PS_OFF 20480
#define PS_STRIDE 168
#define AS_OFF 25856
#define AS_STRIDE 136
#define LDS_N 30208

__global__ __launch_bounds__(256) void attn_kernel(
    const unsigned short* __restrict__ q_bf, const unsigned short* __restrict__ k_bf,
    const float* __restrict__ V, const unsigned short* __restrict__ WvT,
    const float* __restrict__ bv, float* __restrict__ out)
{
    __shared__ unsigned short lds[LDS_N];
    const int tid  = threadIdx.x;
    const int lane = tid & 63;
    const int wv   = tid >> 6;
    const int mt   = wv & 1;
    const int ng   = wv >> 1;      // 0..1

    const int bid  = blockIdx.x;   // 576
    const int bimg = bid / 288;
    const int tidx = bid % 288;
    const int ty = tidx / 24, tx = tidx % 24;
    const int y0 = ty * TH, x0 = tx * TW;

    const int qd = lane >> 4, m = lane & 15;

    // ---- stage V halo -> LDS [halo][128] bf16, swizzled, coalesced ----
    // wave-uniform row per iter; lane = u32 chunk (2 ch). swizzle:
    // u32 col' = (c + ((r>>3)&3)*8) & 63  <=>  u16 col' = (ch + qd*16)&127
    {
        unsigned* __restrict__ vsu = reinterpret_cast<unsigned*>(lds);
        #pragma unroll 8
        for (int i = 0; i < 40; ++i) {
            const int r  = i * 4 + wv;                 // wave-uniform
            const int hy = (r * 6554) >> 16;           // r/10
            const int hx = r - hy * 10;
            const int iy = y0 - 3 + hy, ix = x0 - 3 + hx;
            const bool ok = ((unsigned)iy < HH) & ((unsigned)ix < WW) & (r < NH);
            float2 v = make_float2(0.f, 0.f);
            if (ok)
                v = *reinterpret_cast<const float2*>(
                    V + (size_t)((bimg * HH + iy) * WW + ix) * 128 + lane * 2);
            vsu[r * 64 + ((lane + ((r >> 3) & 3) * 8) & 63)] = packbf(v.x, v.y);
        }
    }

    // ---- scores: all 10 n-tiles per wave (in-wave softmax, no exchange) ----
    short8 qa[2];
    {
        const int p  = mt * 16 + m;
        const int py = p >> 2, px = p & 3;
        const size_t gq = (size_t)(bimg * HH + y0 + py) * WW + (x0 + px);
        #pragma unroll
        for (int ks = 0; ks < 2; ++ks)
            qa[ks] = *reinterpret_cast<const short8*>(q_bf + gq * 64 + ks * 32 + qd * 8);
    }

    f32x4 sc[10];
    #pragma unroll
    for (int nt = 0; nt < 10; ++nt) {
        const int h  = nt * 16 + m;
        const int hy = (h * 6554) >> 16;
        const int hx = h - hy * 10;
        const int iy = y0 - 3 + hy, ix = x0 - 3 + hx;
        const bool ok = ((unsigned)iy < HH) & ((unsigned)ix < WW) & (h < NH);
        const size_t ob = ok ? (size_t)((bimg * HH + iy) * WW + ix) * 64 : 0;
        f32x4 a = {};
        #pragma unroll
        for (int ks = 0; ks < 2; ++ks) {
            const short8 bfr = *reinterpret_cast<const short8*>(k_bf + ob + ks * 32 + qd * 8);
            a = __builtin_amdgcn_mfma_f32_16x16x32_bf16(qa[ks], bfr, a, 0, 0, 0);
        }
        sc[nt] = a;
    }

    // ---- mask + full-row softmax ----
    float mx[4] = {NEGBIG, NEGBIG, NEGBIG, NEGBIG};
    #pragma unroll
    for (int nt = 0; nt < 10; ++nt) {
        const int h  = nt * 16 + m;
        const int hy = (h * 6554) >> 16;
        const int hx = h - hy * 10;
        const int iy = y0 - 3 + hy, ix = x0 - 3 + hx;
        const bool imgok = ((unsigned)iy < HH) & ((unsigned)ix < WW) & (h < NH);
        #pragma unroll
        for (int r = 0; r < 4; ++r) {
            const int p  = mt * 16 + qd * 4 + r;
            const int py = p >> 2, px = p & 3;
            const bool ok = imgok & ((unsigned)(hy - py) <= 6u) & ((unsigned)(hx - px) <= 6u);
            const float s = ok ? sc[nt][r] * 0.125f : NEGBIG;
            sc[nt][r] = s;
            mx[r] = fmaxf(mx[r], s);
        }
    }
    #pragma unroll
    for (int r = 0; r < 4; ++r)
        #pragma unroll
        for (int off = 1; off < 16; off <<= 1)
            mx[r] = fmaxf(mx[r], __shfl_xor(mx[r], off));

    float sm[4] = {0.f, 0.f, 0.f, 0.f};
    #pragma unroll
    for (int nt = 0; nt < 10; ++nt)
        #pragma unroll
        for (int r = 0; r < 4; ++r) {
            const float s = sc[nt][r];
            const float e = (s > -1.0e38f) ? __expf(s - mx[r]) : 0.f;
            sc[nt][r] = e;
            sm[r] += e;
        }
    #pragma unroll
    for (int r = 0; r < 4; ++r) {
        #pragma unroll
        for (int off = 1; off < 16; off <<= 1)
            sm[r] += __shfl_xor(sm[r], off);
        sm[r] = 1.0f / sm[r];
    }

    // ---- write P half (cols ng*5*16 .. +80) ----
    #pragma unroll
    for (int n5 = 0; n5 < 5; ++n5) {
        const int nt = ng * 5 + n5;
        #pragma unroll
        for (int r = 0; r < 4; ++r) {
            const int row = mt * 16 + qd * 4 + r;
            lds[PS_OFF + row * PS_STRIDE + nt * 16 + m] = f2bf(sc[nt][r] * sm[r]);
        }
    }
    __syncthreads();   // B1: P + V-LDS ready

    // ---- PV: A = P (LDS b128), B = V (LDS swizzled u16, conflict-free) ----
    short8 pa[5];
    #pragma unroll
    for (int ks = 0; ks < 5; ++ks)
        pa[ks] = *reinterpret_cast<const short8*>(
            &lds[PS_OFF + (mt * 16 + m) * PS_STRIDE + ks * 32 + qd * 8]);

    f32x4 oacc[4] = {};
    #pragma unroll
    for (int ks = 0; ks < 5; ++ks) {
        const int kbase = ks * 32 + qd * 8;
        #pragma unroll
        for (int n4 = 0; n4 < 4; ++n4) {
            const int colp = (((ng * 4 + n4) * 16 + m) + qd * 16) & 127;  // swizzled ch
            short8 bfr;
            #pragma unroll
            for (int j = 0; j < 8; ++j)
                bfr[j] = (short)lds[VS_OFF + (kbase + j) * 128 + colp];
            oacc[n4] = __builtin_amdgcn_mfma_f32_16x16x32_bf16(pa[ks], bfr, oacc[n4], 0, 0, 0);
        }
    }

    // ---- att -> AS ----
    #pragma unroll
    for (int n4 = 0; n4 < 4; ++n4)
        #pragma unroll
        for (int r = 0; r < 4; ++r) {
            const int row = mt * 16 + qd * 4 + r;
            const int col = (ng * 4 + n4) * 16 + m;
            lds[AS_OFF + row * AS_STRIDE + col] = f2bf(oacc[n4][r]);
        }
    __syncthreads();   // B2: att ready

    // ---- out-proj + bias + relu ----
    short8 aa[4];
    #pragma unroll
    for (int ks = 0; ks < 4; ++ks)
        aa[ks] = *reinterpret_cast<const short8*>(
            &lds[AS_OFF + (mt * 16 + m) * AS_STRIDE + ks * 32 + qd * 8]);

    #pragma unroll
    for (int n4 = 0; n4 < 4; ++n4) {
        const int nt = ng * 4 + n4;
        f32x4 a = {};
        #pragma unroll
        for (int ks = 0; ks < 4; ++ks) {
            const short8 bfr = *reinterpret_cast<const short8*>(
                WvT + (nt * 16 + m) * 128 + ks * 32 + qd * 8);
            a = __builtin_amdgcn_mfma_f32_16x16x32_bf16(aa[ks], bfr, a, 0, 0, 0);
        }
        const int col = nt * 16 + m;
        const float bb = bv[col];
        #pragma unroll
        for (int r = 0; r < 4; ++r) {
            const int p  = mt * 16 + qd * 4 + r;
            const int py = p >> 2, px = p & 3;
            const size_t gp = (size_t)(bimg * HH + y0 + py) * WW + (x0 + px);
            out[gp * 128 + col] = fmaxf(a[r] + bb, 0.f);
        }
    }
}

extern "C" void kernel_launch(void* const* d_in, const int* in_sizes, int n_in,
                              void* d_out, int out_size, void* d_ws, size_t ws_size,
                              hipStream_t stream)
{
    const float* Q  = (const float*)d_in[0];
    const float* K  = (const float*)d_in[1];
    const float* V  = (const float*)d_in[2];
    const float* Wq = (const float*)d_in[3];
    const float* bq = (const float*)d_in[4];
    const float* Wk = (const float*)d_in[5];
    const float* bk = (const float*)d_in[6];
    const float* Wv = (const float*)d_in[7];
    const float* bv = (const float*)d_in[8];
    float* out = (float*)d_out;

    unsigned short* wbase = (unsigned short*)d_ws;     // WqT|WkT|WvT = 32768 u16
    unsigned short* WvT   = wbase + 16384;
    unsigned short* q_bf  = wbase + 32768;             // NPIX*64 bf16
    unsigned short* k_bf  = q_bf + (size_t)NPIX * 64;  // NPIX*64 bf16

    wprep_kernel<<<128, 256, 0, stream>>>(Wq, Wk, Wv, wbase);
    proj_kernel<<<576, 256, 0, stream>>>(Q, K, wbase, bq, bk, q_bf, k_bf);
    attn_kernel<<<576, 256, 0, stream>>>(q_bf, k_bf, V, WvT, bv, out);
}

// Round 9
// 114.014 us; speedup vs baseline: 1.2142x; 1.2142x over previous
//
#include <hip/hip_runtime.h>
#include <math.h>

// Problem constants
#define BH 2
#define HH 96
#define WW 96
#define NPIX (BH*HH*WW)

// Tile geometry: 4x4 pixels per block, halo 10x10 = 100 rows (pad to 128)
#define TH 4
#define TW 4
#define NH 100

#define NEGBIG (-3.0e38f)

typedef __attribute__((ext_vector_type(8))) short short8;
typedef __attribute__((ext_vector_type(4))) float f32x4;

__device__ __forceinline__ unsigned short f2bf(float f) {
    union { float f; unsigned u; } a; a.f = f;
    return (unsigned short)((a.u + 0x7FFFu + ((a.u >> 16) & 1u)) >> 16);
}
__device__ __forceinline__ unsigned packbf(float x, float y) {
    return (unsigned)f2bf(x) | ((unsigned)f2bf(y) << 16);
}

// ---------------------------------------------------------------------------
// Dispatch 1: q/k proj + V->bf16 + WvT (same as R6/R7 best-measured prep).
//   blocks 0..575     : q/k projection -> q_bf/k_bf [NPIX][64] bf16
//   blocks 576..1727  : V fp32 -> v_bf [NPIX][128] bf16 (uint4 writes)
//   blocks 1728..1743 : Wv fp32 -> WvT [128][128] bf16 (transposed)
// ---------------------------------------------------------------------------
__global__ __launch_bounds__(256) void prep_proj_kernel(
    const float* __restrict__ Qg, const float* __restrict__ Kg,
    const float* __restrict__ V,  const float* __restrict__ Wq,
    const float* __restrict__ bq, const float* __restrict__ Wk,
    const float* __restrict__ bk, const float* __restrict__ Wv,
    unsigned short* __restrict__ q_bf, unsigned short* __restrict__ k_bf,
    unsigned short* __restrict__ v_bf, unsigned short* __restrict__ WvT)
{
    const int bid = blockIdx.x;
    const int tid = threadIdx.x;

    if (bid < 576) {
        const int lane = tid & 63;
        const int wvv  = tid >> 6;
        const int gw   = bid * 4 + wvv;            // 0..2303
        const bool isq = gw < 1152;
        const int row0 = (isq ? gw : gw - 1152) * 16;

        const float* __restrict__ X   = isq ? Qg : Kg;
        const float* __restrict__ Wt  = isq ? Wq : Wk;
        const float* __restrict__ bia = isq ? bq : bk;
        unsigned short* __restrict__ Y = isq ? q_bf : k_bf;

        const int qd = lane >> 4, m = lane & 15;

        short8 afr[4];
        #pragma unroll
        for (int ks = 0; ks < 4; ++ks) {
            const float4* __restrict__ src = reinterpret_cast<const float4*>(
                X + (size_t)(row0 + m) * 128 + ks * 32 + qd * 8);
            const float4 a0 = src[0], a1 = src[1];
            short8 f;
            f[0] = (short)f2bf(a0.x); f[1] = (short)f2bf(a0.y);
            f[2] = (short)f2bf(a0.z); f[3] = (short)f2bf(a0.w);
            f[4] = (short)f2bf(a1.x); f[5] = (short)f2bf(a1.y);
            f[6] = (short)f2bf(a1.z); f[7] = (short)f2bf(a1.w);
            afr[ks] = f;
        }

        #pragma unroll
        for (int n = 0; n < 4; ++n) {
            f32x4 acc = {};
            #pragma unroll
            for (int ks = 0; ks < 4; ++ks) {
                short8 bfr;
                #pragma unroll
                for (int j = 0; j < 8; ++j)
                    bfr[j] = (short)f2bf(Wt[(ks * 32 + qd * 8 + j) * 64 + n * 16 + m]);
                acc = __builtin_amdgcn_mfma_f32_16x16x32_bf16(afr[ks], bfr, acc, 0, 0, 0);
            }
            const int col = n * 16 + m;
            const float bb = bia[col];
            #pragma unroll
            for (int r = 0; r < 4; ++r)
                Y[(size_t)(row0 + qd * 4 + r) * 64 + col] = f2bf(acc[r] + bb);
        }
    } else if (bid < 1728) {
        const int idx = (bid - 576) * 256 + tid;          // 0..294911
        const float4* __restrict__ V4 = reinterpret_cast<const float4*>(V);
        const float4 a = V4[idx * 2], b = V4[idx * 2 + 1];
        uint4 o;
        o.x = packbf(a.x, a.y); o.y = packbf(a.z, a.w);
        o.z = packbf(b.x, b.y); o.w = packbf(b.z, b.w);
        reinterpret_cast<uint4*>(v_bf)[idx] = o;
    } else {
        const int base = (bid - 1728) * 1024 + tid * 4;
        #pragma unroll
        for (int i = 0; i < 4; ++i) {
            const int e = base + i;                        // e = n*128 + k
            WvT[e] = f2bf(Wv[(e & 127) * 128 + (e >> 7)]);
        }
    }
}

// ---------------------------------------------------------------------------
// Dispatch 2: neighborhood attention + out-projection. 4x4 tile, 1152 blocks,
// 256 thr (4 waves). Each wave scores ALL 7 halo n-tiles (in-wave softmax,
// no exchange); PV and out-proj split the 128-ch n-dim 4 ways (2 n-tiles
// per wave). P/att in tiny LDS; V via global bf16 gathers (L2/L3-hot).
// 2 barriers. LDS = 9216 B -> occupancy limited only by waves.
// LDS (u16 idx): PS [16][136] @0 | AS [16][136] @2176 | offs 128 ints @4352
// NOTE: offset table MUST be 128 entries (PV K-dim is padded to 128) —
// 112-entry table was R8's crash (wild gathers from poisoned LDS).
// ---------------------------------------------------------------------------
#define PS_OFF 0
#define PS_STRIDE 136
#define AS_OFF 2176
#define AS_STRIDE 136
#define OFF_OFF 4352
#define LDS_N 4608

__global__ __launch_bounds__(256) void attn_kernel(
    const unsigned short* __restrict__ q_bf, const unsigned short* __restrict__ k_bf,
    const unsigned short* __restrict__ v_bf, const unsigned short* __restrict__ WvT,
    const float* __restrict__ bv, float* __restrict__ out)
{
    __shared__ unsigned short lds[LDS_N];
    const int tid  = threadIdx.x;
    const int lane = tid & 63;
    const int wv   = tid >> 6;     // 0..3

    const int bid  = blockIdx.x;   // 1152
    const int bimg = bid / 576;
    const int tidx = bid % 576;
    const int ty = tidx / 24, tx = tidx % 24;
    const int y0 = ty * TH, x0 = tx * TW;

    const int qd = lane >> 4, m = lane & 15;

    int* __restrict__ offsI = reinterpret_cast<int*>(&lds[OFF_OFF]);

    // ---- halo -> pixel-offset table, 128 entries (pad/OOB -> 0) ----
    if (tid < 128) {
        const int r = tid;
        const int hy = (r * 6554) >> 16;            // r/10
        const int hx = r - hy * 10;
        const int iy = y0 - 3 + hy, ix = x0 - 3 + hx;
        int o = 0;
        if (((unsigned)iy < HH) & ((unsigned)ix < WW) & (r < NH))
            o = (bimg * HH + iy) * WW + ix;
        offsI[r] = o;
    }

    // ---- q A-frags: lane m = pixel (py=m>>2, px=m&3) ----
    short8 qa[2];
    {
        const int py = m >> 2, px = m & 3;
        const size_t gq = (size_t)(bimg * HH + y0 + py) * WW + (x0 + px);
        #pragma unroll
        for (int ks = 0; ks < 2; ++ks)
            qa[ks] = *reinterpret_cast<const short8*>(q_bf + gq * 64 + ks * 32 + qd * 8);
    }

    // ---- scores: all 7 n-tiles per wave ----
    f32x4 sc[7];
    #pragma unroll
    for (int nt = 0; nt < 7; ++nt) {
        const int h  = nt * 16 + m;                 // halo row (lane's n)
        const int hy = (h * 6554) >> 16;
        const int hx = h - hy * 10;
        const int iy = y0 - 3 + hy, ix = x0 - 3 + hx;
        const bool ok = ((unsigned)iy < HH) & ((unsigned)ix < WW) & (h < NH);
        const size_t ob = ok ? (size_t)((bimg * HH + iy) * WW + ix) * 64 : 0;
        f32x4 a = {};
        #pragma unroll
        for (int ks = 0; ks < 2; ++ks) {
            const short8 bfr = *reinterpret_cast<const short8*>(k_bf + ob + ks * 32 + qd * 8);
            a = __builtin_amdgcn_mfma_f32_16x16x32_bf16(qa[ks], bfr, a, 0, 0, 0);
        }
        sc[nt] = a;
    }

    // ---- mask + in-wave softmax (rows p = qd*4+r: py=qd, px=r) ----
    float mx[4] = {NEGBIG, NEGBIG, NEGBIG, NEGBIG};
    #pragma unroll
    for (int nt = 0; nt < 7; ++nt) {
        const int h  = nt * 16 + m;
        const int hy = (h * 6554) >> 16;
        const int hx = h - hy * 10;
        const int iy = y0 - 3 + hy, ix = x0 - 3 + hx;
        const bool imgok = ((unsigned)iy < HH) & ((unsigned)ix < WW) & (h < NH);
        #pragma unroll
        for (int r = 0; r < 4; ++r) {
            const bool ok = imgok & ((unsigned)(hy - qd) <= 6u) & ((unsigned)(hx - r) <= 6u);
            const float s = ok ? sc[nt][r] * 0.125f : NEGBIG;
            sc[nt][r] = s;
            mx[r] = fmaxf(mx[r], s);
        }
    }
    #pragma unroll
    for (int r = 0; r < 4; ++r)
        #pragma unroll
        for (int off = 1; off < 16; off <<= 1)
            mx[r] = fmaxf(mx[r], __shfl_xor(mx[r], off));

    float sm[4] = {0.f, 0.f, 0.f, 0.f};
    #pragma unroll
    for (int nt = 0; nt < 7; ++nt)
        #pragma unroll
        for (int r = 0; r < 4; ++r) {
            const float s = sc[nt][r];
            const float e = (s > -1.0e38f) ? __expf(s - mx[r]) : 0.f;
            sc[nt][r] = e;
            sm[r] += e;
        }
    #pragma unroll
    for (int r = 0; r < 4; ++r) {
        #pragma unroll
        for (int off = 1; off < 16; off <<= 1)
            sm[r] += __shfl_xor(sm[r], off);
        sm[r] = 1.0f / sm[r];
    }

    // ---- write P: wave wv owns n-tiles {2wv, 2wv+1}; tile 7 zero pad ----
    #pragma unroll
    for (int nt = 0; nt < 7; ++nt) {
        if ((nt >> 1) == wv) {
            #pragma unroll
            for (int r = 0; r < 4; ++r)
                lds[PS_OFF + (qd * 4 + r) * PS_STRIDE + nt * 16 + m] =
                    f2bf(sc[nt][r] * sm[r]);
        }
    }
    if (wv == 3) {   // zero tile: cols 112..127
        #pragma unroll
        for (int r = 0; r < 4; ++r)
            lds[PS_OFF + (qd * 4 + r) * PS_STRIDE + 112 + m] = 0;
    }
    __syncthreads();   // B1: P + offs ready

    // ---- PV: A = P (LDS b128), B = v_bf global u16 gathers ----
    short8 pa[4];
    #pragma unroll
    for (int ks = 0; ks < 4; ++ks)
        pa[ks] = *reinterpret_cast<const short8*>(
            &lds[PS_OFF + m * PS_STRIDE + ks * 32 + qd * 8]);

    f32x4 oacc[2] = {};
    #pragma unroll
    for (int ks = 0; ks < 4; ++ks) {
        const int kbase = ks * 32 + qd * 8;
        const unsigned short* vb[8];
        #pragma unroll
        for (int j = 0; j < 8; ++j)
            vb[j] = v_bf + (size_t)offsI[kbase + j] * 128;
        #pragma unroll
        for (int n2 = 0; n2 < 2; ++n2) {
            const int ch = (wv * 2 + n2) * 16 + m;
            short8 bfr;
            #pragma unroll
            for (int j = 0; j < 8; ++j)
                bfr[j] = (short)vb[j][ch];
            oacc[n2] = __builtin_amdgcn_mfma_f32_16x16x32_bf16(pa[ks], bfr, oacc[n2], 0, 0, 0);
        }
    }

    // ---- att -> AS ----
    #pragma unroll
    for (int n2 = 0; n2 < 2; ++n2)
        #pragma unroll
        for (int r = 0; r < 4; ++r)
            lds[AS_OFF + (qd * 4 + r) * AS_STRIDE + (wv * 2 + n2) * 16 + m] =
                f2bf(oacc[n2][r]);
    __syncthreads();   // B2: att ready

    // ---- out-proj + bias + relu ----
    short8 aa[4];
    #pragma unroll
    for (int ks = 0; ks < 4; ++ks)
        aa[ks] = *reinterpret_cast<const short8*>(
            &lds[AS_OFF + m * AS_STRIDE + ks * 32 + qd * 8]);

    #pragma unroll
    for (int n2 = 0; n2 < 2; ++n2) {
        const int nt = wv * 2 + n2;
        f32x4 a = {};
        #pragma unroll
        for (int ks = 0; ks < 4; ++ks) {
            const short8 bfr = *reinterpret_cast<const short8*>(
                WvT + (nt * 16 + m) * 128 + ks * 32 + qd * 8);
            a = __builtin_amdgcn_mfma_f32_16x16x32_bf16(aa[ks], bfr, a, 0, 0, 0);
        }
        const int col = nt * 16 + m;
        const float bb = bv[col];
        #pragma unroll
        for (int r = 0; r < 4; ++r) {
            const int py = qd, px = r;
            const size_t gp = (size_t)(bimg * HH + y0 + py) * WW + (x0 + px);
            out[gp * 128 + col] = fmaxf(a[r] + bb, 0.f);
        }
    }
}

extern "C" void kernel_launch(void* const* d_in, const int* in_sizes, int n_in,
                              void* d_out, int out_size, void* d_ws, size_t ws_size,
                              hipStream_t stream)
{
    const float* Q  = (const float*)d_in[0];
    const float* K  = (const float*)d_in[1];
    const float* V  = (const float*)d_in[2];
    const float* Wq = (const float*)d_in[3];
    const float* bq = (const float*)d_in[4];
    const float* Wk = (const float*)d_in[5];
    const float* bk = (const float*)d_in[6];
    const float* Wv = (const float*)d_in[7];
    const float* bv = (const float*)d_in[8];
    float* out = (float*)d_out;

    unsigned short* wbase = (unsigned short*)d_ws;
    unsigned short* WvT   = wbase + 16384;
    unsigned short* q_bf  = wbase + 32768;             // NPIX*64 bf16
    unsigned short* k_bf  = q_bf + (size_t)NPIX * 64;  // NPIX*64 bf16
    unsigned short* v_bf  = k_bf + (size_t)NPIX * 64;  // NPIX*128 bf16

    prep_proj_kernel<<<1744, 256, 0, stream>>>(Q, K, V, Wq, bq, Wk, bk, Wv,
                                               q_bf, k_bf, v_bf, WvT);
    attn_kernel<<<1152, 256, 0, stream>>>(q_bf, k_bf, v_bf, WvT, bv, out);
}

// Round 10
// 109.925 us; speedup vs baseline: 1.2594x; 1.0372x over previous
//
#include <hip/hip_runtime.h>
#include <math.h>

// Problem constants
#define BH 2
#define HH 96
#define WW 96
#define NPIX (BH*HH*WW)

// Attention tile geometry: 8x4 pixels, halo 14x10 = 140 (pad 160)
#define TH 8
#define TW 4
#define NH 140
#define NHP 160

#define NEGBIG (-3.0e38f)

typedef __attribute__((ext_vector_type(8))) short short8;
typedef __attribute__((ext_vector_type(4))) float f32x4;

__device__ __forceinline__ unsigned short f2bf(float f) {
    union { float f; unsigned u; } a; a.f = f;
    return (unsigned short)((a.u + 0x7FFFu + ((a.u >> 16) & 1u)) >> 16);
}
__device__ __forceinline__ unsigned packbf(float x, float y) {
    return (unsigned)f2bf(x) | ((unsigned)f2bf(y) << 16);
}

// ---------------------------------------------------------------------------
// Dispatch 1: q/k proj + V->bf16 + WvT.
//   blocks 0..287   : q-projection (W staged transposed in LDS, b128 B-frags)
//   blocks 288..575 : k-projection (same)
//   blocks 576..1727: V fp32 -> v_bf [NPIX][128] bf16
//   blocks 1728..1743: Wv -> WvT [128][128] bf16
// ---------------------------------------------------------------------------
#define WT_STRIDE 136   // u16, 16B-aligned rows

__global__ __launch_bounds__(256) void prep_proj_kernel(
    const float* __restrict__ Qg, const float* __restrict__ Kg,
    const float* __restrict__ V,  const float* __restrict__ Wq,
    const float* __restrict__ bq, const float* __restrict__ Wk,
    const float* __restrict__ bk, const float* __restrict__ Wv,
    unsigned short* __restrict__ q_bf, unsigned short* __restrict__ k_bf,
    unsigned short* __restrict__ v_bf, unsigned short* __restrict__ WvT)
{
    __shared__ unsigned short WT[64 * WT_STRIDE];   // 17.4 KB
    const int bid = blockIdx.x;
    const int tid = threadIdx.x;

    if (bid < 576) {
        const bool isq = bid < 288;
        const float* __restrict__ X   = isq ? Qg : Kg;
        const float* __restrict__ Wt  = isq ? Wq : Wk;
        const float* __restrict__ bia = isq ? bq : bk;
        unsigned short* __restrict__ Y = isq ? q_bf : k_bf;

        // stage W[128][64] fp32 -> WT[64][128] bf16 (transposed), coalesced
        {
            const float4* __restrict__ W4 = reinterpret_cast<const float4*>(Wt);
            #pragma unroll
            for (int i = 0; i < 8; ++i) {
                const int e  = tid + 256 * i;     // float4 idx 0..2047
                const int k  = e >> 4;            // 0..127
                const int n4 = (e & 15) * 4;      // 0..60
                const float4 v = W4[e];
                WT[(n4 + 0) * WT_STRIDE + k] = f2bf(v.x);
                WT[(n4 + 1) * WT_STRIDE + k] = f2bf(v.y);
                WT[(n4 + 2) * WT_STRIDE + k] = f2bf(v.z);
                WT[(n4 + 3) * WT_STRIDE + k] = f2bf(v.w);
            }
        }
        __syncthreads();

        const int lane = tid & 63;
        const int wvv  = tid >> 6;
        const int row0 = ((bid % 288) * 4 + wvv) * 16;
        const int qd = lane >> 4, m = lane & 15;

        short8 afr[4];
        #pragma unroll
        for (int ks = 0; ks < 4; ++ks) {
            const float4* __restrict__ src = reinterpret_cast<const float4*>(
                X + (size_t)(row0 + m) * 128 + ks * 32 + qd * 8);
            const float4 a0 = src[0], a1 = src[1];
            short8 f;
            f[0] = (short)f2bf(a0.x); f[1] = (short)f2bf(a0.y);
            f[2] = (short)f2bf(a0.z); f[3] = (short)f2bf(a0.w);
            f[4] = (short)f2bf(a1.x); f[5] = (short)f2bf(a1.y);
            f[6] = (short)f2bf(a1.z); f[7] = (short)f2bf(a1.w);
            afr[ks] = f;
        }

        #pragma unroll
        for (int n = 0; n < 4; ++n) {
            f32x4 acc = {};
            #pragma unroll
            for (int ks = 0; ks < 4; ++ks) {
                const short8 bfr = *reinterpret_cast<const short8*>(
                    &WT[(n * 16 + m) * WT_STRIDE + ks * 32 + qd * 8]);
                acc = __builtin_amdgcn_mfma_f32_16x16x32_bf16(afr[ks], bfr, acc, 0, 0, 0);
            }
            const int col = n * 16 + m;
            const float bb = bia[col];
            #pragma unroll
            for (int r = 0; r < 4; ++r)
                Y[(size_t)(row0 + qd * 4 + r) * 64 + col] = f2bf(acc[r] + bb);
        }
    } else if (bid < 1728) {
        const int idx = (bid - 576) * 256 + tid;          // 0..294911
        const float4* __restrict__ V4 = reinterpret_cast<const float4*>(V);
        const float4 a = V4[idx * 2], b = V4[idx * 2 + 1];
        uint4 o;
        o.x = packbf(a.x, a.y); o.y = packbf(a.z, a.w);
        o.z = packbf(b.x, b.y); o.w = packbf(b.z, b.w);
        reinterpret_cast<uint4*>(v_bf)[idx] = o;
    } else {
        const int base = (bid - 1728) * 1024 + tid * 4;
        #pragma unroll
        for (int i = 0; i < 4; ++i) {
            const int e = base + i;                        // e = n*128 + k
            WvT[e] = f2bf(Wv[(e & 127) * 128 + (e >> 7)]);
        }
    }
}

// ---------------------------------------------------------------------------
// Dispatch 2: neighborhood attention + out-projection.
// 576 blocks x 512 thr (8 waves): wave = (mt = wv&1 row-half of 16 px,
// ng = wv>>1 n-quarter). Scores: {3,3,2,2} n-tiles/wave, 4-way softmax
// partial merge via LDS; PV + out-proj: 2 ch-tiles/wave. k/V/WvT read
// straight from global (L2/L3-hot) via offset table. 3 barriers.
// LDS (u16): PS[32][168] @0 | AS[32][136] @5376 | SM 256f @9728 |
//            offs 160 int @10240 -> 10560 u16 = 21120 B.
// ---------------------------------------------------------------------------
#define PS_OFF 0
#define PS_STRIDE 168
#define AS_OFF 5376
#define AS_STRIDE 136
#define SM_OFF 9728
#define OFF_OFF 10240
#define LDS_N 10560

__global__ __launch_bounds__(512) void attn_kernel(
    const unsigned short* __restrict__ q_bf, const unsigned short* __restrict__ k_bf,
    const unsigned short* __restrict__ v_bf, const unsigned short* __restrict__ WvT,
    const float* __restrict__ bv, float* __restrict__ out)
{
    __shared__ unsigned short lds[LDS_N];
    const int tid  = threadIdx.x;
    const int lane = tid & 63;
    const int wv   = tid >> 6;     // 0..7
    const int mt   = wv & 1;
    const int ng   = wv >> 1;      // 0..3

    const int bid  = blockIdx.x;   // 576
    const int bimg = bid / 288;
    const int tidx = bid % 288;
    const int ty = tidx / 24, tx = tidx % 24;
    const int y0 = ty * TH, x0 = tx * TW;

    const int qd = lane >> 4, m = lane & 15;

    int*   __restrict__ offsI = reinterpret_cast<int*>(&lds[OFF_OFF]);
    float* __restrict__ smf   = reinterpret_cast<float*>(&lds[SM_OFF]);

    // ---- offs table (write only; first consumed after B1) ----
    if (tid < NHP) {
        const int r = tid;
        const int hy = (r * 6554) >> 16;            // r/10
        const int hx = r - hy * 10;
        const int iy = y0 - 3 + hy, ix = x0 - 3 + hx;
        int o = -1;
        if (((unsigned)iy < HH) & ((unsigned)ix < WW) & (r < NH))
            o = (bimg * HH + iy) * WW + ix;
        offsI[r] = o;
    }

    // ---- q A-frags ----
    short8 qa[2];
    {
        const int py = mt * 4 + (m >> 2), px = m & 3;
        const size_t gq = (size_t)(bimg * HH + y0 + py) * WW + (x0 + px);
        #pragma unroll
        for (int ks = 0; ks < 2; ++ks)
            qa[ks] = *reinterpret_cast<const short8*>(q_bf + gq * 64 + ks * 32 + qd * 8);
    }

    // ---- scores: wave's n-tiles (addresses computed inline) ----
    const int ntbase = (ng < 2) ? ng * 3 : 6 + (ng - 2) * 2;
    const int ntcnt  = (ng < 2) ? 3 : 2;

    f32x4 sc[3];
    #pragma unroll
    for (int n5 = 0; n5 < 3; ++n5) {
        if (n5 >= ntcnt) break;
        const int h  = (ntbase + n5) * 16 + m;
        const int hy = (h * 6554) >> 16;
        const int hx = h - hy * 10;
        const int iy = y0 - 3 + hy, ix = x0 - 3 + hx;
        const bool ok = ((unsigned)iy < HH) & ((unsigned)ix < WW) & (h < NH);
        const size_t ob = ok ? (size_t)((bimg * HH + iy) * WW + ix) * 64 : 0;
        f32x4 a = {};
        #pragma unroll
        for (int ks = 0; ks < 2; ++ks) {
            const short8 bfr = *reinterpret_cast<const short8*>(k_bf + ob + ks * 32 + qd * 8);
            a = __builtin_amdgcn_mfma_f32_16x16x32_bf16(qa[ks], bfr, a, 0, 0, 0);
        }
        sc[n5] = a;
    }

    // ---- mask + per-group softmax partials (rows: py=mt*4+qd, px=r) ----
    float mx[4] = {NEGBIG, NEGBIG, NEGBIG, NEGBIG};
    #pragma unroll
    for (int n5 = 0; n5 < 3; ++n5) {
        if (n5 >= ntcnt) break;
        const int h  = (ntbase + n5) * 16 + m;
        const int hy = (h * 6554) >> 16;
        const int hx = h - hy * 10;
        const int iy = y0 - 3 + hy, ix = x0 - 3 + hx;
        const bool imgok = ((unsigned)iy < HH) & ((unsigned)ix < WW) & (h < NH);
        const int py = mt * 4 + qd;
        #pragma unroll
        for (int r = 0; r < 4; ++r) {
            const bool ok = imgok & ((unsigned)(hy - py) <= 6u) & ((unsigned)(hx - r) <= 6u);
            const float s = ok ? sc[n5][r] * 0.125f : NEGBIG;
            sc[n5][r] = s;
            mx[r] = fmaxf(mx[r], s);
        }
    }
    #pragma unroll
    for (int r = 0; r < 4; ++r)
        #pragma unroll
        for (int off = 1; off < 16; off <<= 1)
            mx[r] = fmaxf(mx[r], __shfl_xor(mx[r], off));

    float sm[4] = {0.f, 0.f, 0.f, 0.f};
    #pragma unroll
    for (int n5 = 0; n5 < 3; ++n5) {
        if (n5 >= ntcnt) break;
        #pragma unroll
        for (int r = 0; r < 4; ++r) {
            const float s = sc[n5][r];
            const float e = (s > -1.0e38f) ? __expf(s - mx[r]) : 0.f;
            sc[n5][r] = e;
            sm[r] += e;
        }
    }
    #pragma unroll
    for (int r = 0; r < 4; ++r)
        #pragma unroll
        for (int off = 1; off < 16; off <<= 1)
            sm[r] += __shfl_xor(sm[r], off);

    if (m == 0) {
        #pragma unroll
        for (int r = 0; r < 4; ++r) {
            const int row = mt * 16 + qd * 4 + r;
            smf[row * 4 + ng]       = mx[r];
            smf[128 + row * 4 + ng] = sm[r];
        }
    }
    __syncthreads();   // B1: SM partials + offs ready

    // ---- merge 4-way partials ----
    float fac[4];
    #pragma unroll
    for (int r = 0; r < 4; ++r) {
        const int row = mt * 16 + qd * 4 + r;
        float M = smf[row * 4 + 0];
        M = fmaxf(M, smf[row * 4 + 1]);
        M = fmaxf(M, smf[row * 4 + 2]);
        M = fmaxf(M, smf[row * 4 + 3]);
        float S = 0.f;
        #pragma unroll
        for (int g = 0; g < 4; ++g) {
            const float mg = smf[row * 4 + g];
            const float eg = (mg > -1.0e38f) ? __expf(mg - M) : 0.f;
            S += smf[128 + row * 4 + g] * eg;
        }
        const float eo = (mx[r] > -1.0e38f) ? __expf(mx[r] - M) : 0.f;
        fac[r] = eo / S;
    }

    // ---- write P quarter (bf16) ----
    #pragma unroll
    for (int n5 = 0; n5 < 3; ++n5) {
        if (n5 >= ntcnt) break;
        #pragma unroll
        for (int r = 0; r < 4; ++r) {
            const int row = mt * 16 + qd * 4 + r;
            const int col = (ntbase + n5) * 16 + m;
            lds[PS_OFF + row * PS_STRIDE + col] = f2bf(sc[n5][r] * fac[r]);
        }
    }
    __syncthreads();   // B2: P complete

    // ---- PV: A = P (LDS b128), B = v_bf global u16 gathers ----
    short8 pa[5];
    #pragma unroll
    for (int ks = 0; ks < 5; ++ks)
        pa[ks] = *reinterpret_cast<const short8*>(
            &lds[PS_OFF + (mt * 16 + m) * PS_STRIDE + ks * 32 + qd * 8]);

    f32x4 oacc[2] = {};
    #pragma unroll
    for (int ks = 0; ks < 5; ++ks) {
        const int kbase = ks * 32 + qd * 8;
        const unsigned short* vb[8];
        #pragma unroll
        for (int j = 0; j < 8; ++j) {
            const int o = offsI[kbase + j];
            vb[j] = v_bf + (size_t)(o < 0 ? 0 : o) * 128;
        }
        #pragma unroll
        for (int n2 = 0; n2 < 2; ++n2) {
            const int ch = (ng * 2 + n2) * 16 + m;
            short8 bfr;
            #pragma unroll
            for (int j = 0; j < 8; ++j)
                bfr[j] = (short)vb[j][ch];
            oacc[n2] = __builtin_amdgcn_mfma_f32_16x16x32_bf16(pa[ks], bfr, oacc[n2], 0, 0, 0);
        }
    }

    // ---- att -> AS ----
    #pragma unroll
    for (int n2 = 0; n2 < 2; ++n2)
        #pragma unroll
        for (int r = 0; r < 4; ++r) {
            const int row = mt * 16 + qd * 4 + r;
            const int col = (ng * 2 + n2) * 16 + m;
            lds[AS_OFF + row * AS_STRIDE + col] = f2bf(oacc[n2][r]);
        }
    __syncthreads();   // B3: att complete

    // ---- out-proj + bias + relu ----
    short8 aa[4];
    #pragma unroll
    for (int ks = 0; ks < 4; ++ks)
        aa[ks] = *reinterpret_cast<const short8*>(
            &lds[AS_OFF + (mt * 16 + m) * AS_STRIDE + ks * 32 + qd * 8]);

    #pragma unroll
    for (int n2 = 0; n2 < 2; ++n2) {
        const int nt = ng * 2 + n2;
        f32x4 a = {};
        #pragma unroll
        for (int ks = 0; ks < 4; ++ks) {
            const short8 bfr = *reinterpret_cast<const short8*>(
                WvT + (nt * 16 + m) * 128 + ks * 32 + qd * 8);
            a = __builtin_amdgcn_mfma_f32_16x16x32_bf16(aa[ks], bfr, a, 0, 0, 0);
        }
        const int col = nt * 16 + m;
        const float bb = bv[col];
        #pragma unroll
        for (int r = 0; r < 4; ++r) {
            const int py = mt * 4 + qd, px = r;
            const size_t gp = (size_t)(bimg * HH + y0 + py) * WW + (x0 + px);
            out[gp * 128 + col] = fmaxf(a[r] + bb, 0.f);
        }
    }
}

extern "C" void kernel_launch(void* const* d_in, const int* in_sizes, int n_in,
                              void* d_out, int out_size, void* d_ws, size_t ws_size,
                              hipStream_t stream)
{
    const float* Q  = (const float*)d_in[0];
    const float* K  = (const float*)d_in[1];
    const float* V  = (const float*)d_in[2];
    const float* Wq = (const float*)d_in[3];
    const float* bq = (const float*)d_in[4];
    const float* Wk = (const float*)d_in[5];
    const float* bk = (const float*)d_in[6];
    const float* Wv = (const float*)d_in[7];
    const float* bv = (const float*)d_in[8];
    float* out = (float*)d_out;

    unsigned short* wbase = (unsigned short*)d_ws;
    unsigned short* WvT   = wbase + 16384;
    unsigned short* q_bf  = wbase + 32768;             // NPIX*64 bf16
    unsigned short* k_bf  = q_bf + (size_t)NPIX * 64;  // NPIX*64 bf16
    unsigned short* v_bf  = k_bf + (size_t)NPIX * 64;  // NPIX*128 bf16

    prep_proj_kernel<<<1744, 256, 0, stream>>>(Q, K, V, Wq, bq, Wk, bk, Wv,
                                               q_bf, k_bf, v_bf, WvT);
    attn_kernel<<<576, 512, 0, stream>>>(q_bf, k_bf, v_bf, WvT, bv, out);
}